// Round 5
// baseline (186.120 us; speedup 1.0000x reference)
//
#include <hip/hip_runtime.h>

#define NVOX 200000
#define TILE 256
#define ETILE 1024          // max entries per 256-voxel tile (mean ~750, sigma ~21)
#define NTILES ((NVOX + TILE - 1) / TILE)   // 782

// ---------------- 16x16 FMA micro-kernel: acc[16] += g[16] @ W(16x16) from LDS ----------------
__device__ __forceinline__ void fma16x16(const float4* __restrict__ wrow,
                                         float4 f0, float4 f1, float4 f2, float4 f3,
                                         float acc[16]) {
    const float g[16] = {f0.x, f0.y, f0.z, f0.w, f1.x, f1.y, f1.z, f1.w,
                         f2.x, f2.y, f2.z, f2.w, f3.x, f3.y, f3.z, f3.w};
    #pragma unroll
    for (int cc = 0; cc < 16; ++cc) {
        float gc = g[cc];
        float4 w0 = wrow[cc * 4 + 0];
        float4 w1 = wrow[cc * 4 + 1];
        float4 w2 = wrow[cc * 4 + 2];
        float4 w3 = wrow[cc * 4 + 3];
        acc[0]  += gc * w0.x; acc[1]  += gc * w0.y; acc[2]  += gc * w0.z; acc[3]  += gc * w0.w;
        acc[4]  += gc * w1.x; acc[5]  += gc * w1.y; acc[6]  += gc * w1.z; acc[7]  += gc * w1.w;
        acc[8]  += gc * w2.x; acc[9]  += gc * w2.y; acc[10] += gc * w2.z; acc[11] += gc * w2.w;
        acc[12] += gc * w3.x; acc[13] += gc * w3.y; acc[14] += gc * w3.z; acc[15] += gc * w3.w;
    }
}

// ---------------- K1: coalesced compact + per-tile k-sorted entry list + conv0 ----------------
__global__ __launch_bounds__(256) void k1_compact_conv0(
    const float* __restrict__ feats,  // [N,4]
    const int* __restrict__ nbr,      // [N,27]
    const float* __restrict__ W,      // [27,4,16]
    const float* __restrict__ s, const float* __restrict__ b,
    int* __restrict__ gEnt,           // [NTILES,ETILE] packed (idx<<14)|(k<<9)|nloc, k-sorted per tile
    int* __restrict__ tileCnt,        // [NTILES]
    float* __restrict__ x) {          // [N,16]
    __shared__ int   lnbr[TILE * 27]; // 27.6 KB
    __shared__ float Wl[27 * 68];     // 7.3 KB
    __shared__ int   khist[27];
    __shared__ int   kbase[28];
    __shared__ int   eloc[ETILE];     // 4 KB
    int t = threadIdx.x;
    int tile = blockIdx.x;
    int base = tile * TILE;
    for (int i = t; i < 27 * 64; i += 256)
        Wl[(i >> 6) * 68 + (i & 63)] = W[i];
    if (t < 27) khist[t] = 0;
    int nv = NVOX - base; if (nv > TILE) nv = TILE;
    const int* gsrc = nbr + base * 27;
    for (int i = t; i < nv * 27; i += 256)
        lnbr[i] = gsrc[i];            // fully coalesced
    __syncthreads();

    int c = 0;
    int* row = lnbr + t * 27;
    if (t < nv) {
        #pragma unroll
        for (int k = 0; k < 27; ++k) {
            int idx = row[k];
            if (idx >= 0) {
                row[c] = (idx << 5) | k;   // in-place compaction (c <= k)
                atomicAdd(&khist[k], 1);
                ++c;
            }
        }
    }
    __syncthreads();
    if (t == 0) {
        int a = 0;
        for (int k = 0; k < 27; ++k) { kbase[k] = a; a += khist[k]; }
        kbase[27] = a;
        tileCnt[tile] = a < ETILE ? a : ETILE;
    }
    __syncthreads();
    if (t < 27) khist[t] = 0;          // reuse as per-bin cursor
    __syncthreads();
    if (t < nv) {
        for (int j = 0; j < c; ++j) {
            int e = row[j];
            int k = e & 31;
            int idx = e >> 5;
            int pos = kbase[k] + atomicAdd(&khist[k], 1);
            if (pos < ETILE)
                eloc[pos] = (idx << 14) | (k << 9) | t;
        }
    }
    __syncthreads();
    int tot = kbase[27] < ETILE ? kbase[27] : ETILE;
    for (int i = t; i < tot; i += 256)
        gEnt[tile * ETILE + i] = eloc[i];   // coalesced dump

    // conv0: uniform loop over this thread's compacted entries (from LDS)
    if (t >= nv) return;
    float acc[16];
    #pragma unroll
    for (int d = 0; d < 16; ++d) acc[d] = 0.f;
    int e = row[0];                   // c >= 1 (center k=13 always present)
    float4 f = *(const float4*)(feats + (e >> 5) * 4);
    int j = 0;
    while (true) {
        bool more = (++j < c);
        int en = e; float4 fn = f;
        if (more) {
            en = row[j];
            fn = *(const float4*)(feats + (en >> 5) * 4);
        }
        {
            const float4* wrow = (const float4*)(Wl + (e & 31) * 68);
            float g[4] = {f.x, f.y, f.z, f.w};
            #pragma unroll
            for (int cc = 0; cc < 4; ++cc) {
                float gc = g[cc];
                float4 w0 = wrow[cc * 4 + 0];
                float4 w1 = wrow[cc * 4 + 1];
                float4 w2 = wrow[cc * 4 + 2];
                float4 w3 = wrow[cc * 4 + 3];
                acc[0]  += gc * w0.x; acc[1]  += gc * w0.y; acc[2]  += gc * w0.z; acc[3]  += gc * w0.w;
                acc[4]  += gc * w1.x; acc[5]  += gc * w1.y; acc[6]  += gc * w1.z; acc[7]  += gc * w1.w;
                acc[8]  += gc * w2.x; acc[9]  += gc * w2.y; acc[10] += gc * w2.z; acc[11] += gc * w2.w;
                acc[12] += gc * w3.x; acc[13] += gc * w3.y; acc[14] += gc * w3.z; acc[15] += gc * w3.w;
            }
        }
        if (!more) break;
        e = en; f = fn;
    }
    int n = base + t;
    float4* o = (float4*)(x + n * 16);
    #pragma unroll
    for (int q = 0; q < 4; ++q) {
        float4 r;
        float v0 = acc[q * 4 + 0] * s[q * 4 + 0] + b[q * 4 + 0];
        float v1 = acc[q * 4 + 1] * s[q * 4 + 1] + b[q * 4 + 1];
        float v2 = acc[q * 4 + 2] * s[q * 4 + 2] + b[q * 4 + 2];
        float v3 = acc[q * 4 + 3] * s[q * 4 + 3] + b[q * 4 + 3];
        r.x = v0 > 0.f ? v0 : 0.f;
        r.y = v1 > 0.f ? v1 : 0.f;
        r.z = v2 > 0.f ? v2 : 0.f;
        r.w = v3 > 0.f ? v3 : 0.f;
        o[q] = r;
    }
}

// ---------------- per-tile entry loop: k-uniform broadcast W, native ds_add_f32 scatter ----------------
__device__ __forceinline__ void conv_tile_accum(const float* __restrict__ fin,
                                                const int* __restrict__ ep, int cntE,
                                                const float* __restrict__ Wl,
                                                float* __restrict__ ot, int t) {
    int i = t;
    if (i >= cntE) return;
    unsigned e = (unsigned)ep[i];
    const float4* fp = (const float4*)(fin + (e >> 14) * 16);
    float4 f0 = fp[0], f1 = fp[1], f2 = fp[2], f3 = fp[3];
    while (true) {
        int i2 = i + 256;
        bool more = (i2 < cntE);
        unsigned e2 = e;
        float4 g0 = f0, g1 = f1, g2 = f2, g3 = f3;
        if (more) {
            e2 = (unsigned)ep[i2];    // prefetch next entry + feature row
            const float4* fq = (const float4*)(fin + (e2 >> 14) * 16);
            g0 = fq[0]; g1 = fq[1]; g2 = fq[2]; g3 = fq[3];
        }
        int k  = (e >> 9) & 31;       // wave-uniform except bin-boundary waves -> W reads broadcast
        int nl = e & 511;
        float acc[16];
        #pragma unroll
        for (int d = 0; d < 16; ++d) acc[d] = 0.f;
        fma16x16((const float4*)(Wl + k * 256), f0, f1, f2, f3, acc);
        float* orow = ot + nl * 17;   // stride 17: coprime with 32 banks -> 2 lanes/bank (free)
        #pragma unroll
        for (int d = 0; d < 16; ++d)
            unsafeAtomicAdd(&orow[d], acc[d]);  // native ds_add_f32, no CAS loop, no return dep
        if (!more) break;
        i = i2; e = e2; f0 = g0; f1 = g1; f2 = g2; f3 = g3;
    }
}

// ---------------- K2: conv1 (16->16), relu(conv*s+b) ----------------
__global__ __launch_bounds__(256) void k2_conv1(
    const float* __restrict__ fin,    // x [N,16]
    const int* __restrict__ gEnt, const int* __restrict__ tileCnt,
    const float* __restrict__ W,      // [27,16,16]
    const float* __restrict__ s, const float* __restrict__ b,
    float* __restrict__ out) {        // h [N,16]
    __shared__ float Wl[27 * 256];    // 27 KB, unpadded (broadcast reads)
    __shared__ float ot[TILE * 17];   // 17.4 KB
    int t = threadIdx.x;
    int tile = blockIdx.x;
    for (int i = t; i < 27 * 256; i += 256) Wl[i] = W[i];
    for (int i = t; i < TILE * 17; i += 256) ot[i] = 0.f;
    __syncthreads();
    conv_tile_accum(fin, gEnt + tile * ETILE, tileCnt[tile], Wl, ot, t);
    __syncthreads();
    int n = tile * TILE + t;
    if (n >= NVOX) return;
    const float* orow = ot + t * 17;
    float4* o = (float4*)(out + n * 16);
    #pragma unroll
    for (int q = 0; q < 4; ++q) {
        float4 r;
        float v0 = orow[q * 4 + 0] * s[q * 4 + 0] + b[q * 4 + 0];
        float v1 = orow[q * 4 + 1] * s[q * 4 + 1] + b[q * 4 + 1];
        float v2 = orow[q * 4 + 2] * s[q * 4 + 2] + b[q * 4 + 2];
        float v3 = orow[q * 4 + 3] * s[q * 4 + 3] + b[q * 4 + 3];
        r.x = v0 > 0.f ? v0 : 0.f;
        r.y = v1 > 0.f ? v1 : 0.f;
        r.z = v2 > 0.f ? v2 : 0.f;
        r.w = v3 > 0.f ? v3 : 0.f;
        o[q] = r;
    }
}

// ---------------- K3: conv2 + residual + relu + final 16->3 linear ----------------
__global__ __launch_bounds__(256) void k3_conv2_final(
    const float* __restrict__ fin,    // h [N,16]
    const int* __restrict__ gEnt, const int* __restrict__ tileCnt,
    const float* __restrict__ W,      // [27,16,16]
    const float* __restrict__ s, const float* __restrict__ b,
    const float* __restrict__ idn,    // x [N,16]
    const float* __restrict__ Wlin,   // [16,3]
    const float* __restrict__ blin,   // [3]
    float* __restrict__ out) {        // [N,3]
    __shared__ float Wl[27 * 256];
    __shared__ float ot[TILE * 17];
    int t = threadIdx.x;
    int tile = blockIdx.x;
    for (int i = t; i < 27 * 256; i += 256) Wl[i] = W[i];
    for (int i = t; i < TILE * 17; i += 256) ot[i] = 0.f;
    __syncthreads();
    conv_tile_accum(fin, gEnt + tile * ETILE, tileCnt[tile], Wl, ot, t);
    __syncthreads();
    int n = tile * TILE + t;
    if (n >= NVOX) return;
    const float* orow = ot + t * 17;
    const float4* ip = (const float4*)(idn + n * 16);
    float4 i0 = ip[0], i1 = ip[1], i2 = ip[2], i3 = ip[3];
    float id[16] = {i0.x, i0.y, i0.z, i0.w, i1.x, i1.y, i1.z, i1.w,
                    i2.x, i2.y, i2.z, i2.w, i3.x, i3.y, i3.z, i3.w};
    float o0 = blin[0], o1 = blin[1], o2 = blin[2];
    #pragma unroll
    for (int d = 0; d < 16; ++d) {
        float v = orow[d] * s[d] + b[d] + id[d];
        v = v > 0.f ? v : 0.f;
        o0 += v * Wlin[d * 3 + 0];
        o1 += v * Wlin[d * 3 + 1];
        o2 += v * Wlin[d * 3 + 2];
    }
    out[n * 3 + 0] = o0;
    out[n * 3 + 1] = o1;
    out[n * 3 + 2] = o2;
}

extern "C" void kernel_launch(void* const* d_in, const int* in_sizes, int n_in,
                              void* d_out, int out_size, void* d_ws, size_t ws_size,
                              hipStream_t stream) {
    const float* feats = (const float*)d_in[0];
    const int*   nbr   = (const int*)d_in[1];
    const float* W0    = (const float*)d_in[2];
    const float* s0    = (const float*)d_in[3];
    const float* b0    = (const float*)d_in[4];
    const float* W1    = (const float*)d_in[5];
    const float* s1    = (const float*)d_in[6];
    const float* b1    = (const float*)d_in[7];
    const float* W2    = (const float*)d_in[8];
    const float* s2    = (const float*)d_in[9];
    const float* b2    = (const float*)d_in[10];
    const float* Wlin  = (const float*)d_in[11];
    const float* blin  = (const float*)d_in[12];
    float* out = (float*)d_out;

    char* ws = (char*)d_ws;
    int*   gEnt    = (int*)(ws);                 // NTILES*ETILE*4 = 3,203,072
    int*   tileCnt = (int*)(ws + 3203072);       // 3,128
    float* x       = (float*)(ws + 3208192);     // 12,800,000
    float* h       = (float*)(ws + 16008192);    // 12,800,000

    k1_compact_conv0<<<NTILES, 256, 0, stream>>>(feats, nbr, W0, s0, b0, gEnt, tileCnt, x);
    k2_conv1<<<NTILES, 256, 0, stream>>>(x, gEnt, tileCnt, W1, s1, b1, h);
    k3_conv2_final<<<NTILES, 256, 0, stream>>>(h, gEnt, tileCnt, W2, s2, b2, x, Wlin, blin, out);
}

// Round 7
// 127.288 us; speedup vs baseline: 1.4622x; 1.4622x over previous
//
#include <hip/hip_runtime.h>

#define NVOX 200000
#define TILE 128
#define ETG 1024            // global entry cap per tile (>= max tile total; R4 evidence: 256-tile totals <= 1024)
#define WIN 512             // LDS partial-row window (covers ~all tiles in one pass)
#define NTILES ((NVOX + TILE - 1) / TILE)   // 1563

// ---------------- 16x16 FMA micro-kernel: acc[16] += g[16] @ W(16x16) ----------------
__device__ __forceinline__ void fma16x16(const float4* __restrict__ wrow,
                                         float4 f0, float4 f1, float4 f2, float4 f3,
                                         float acc[16]) {
    const float g[16] = {f0.x, f0.y, f0.z, f0.w, f1.x, f1.y, f1.z, f1.w,
                         f2.x, f2.y, f2.z, f2.w, f3.x, f3.y, f3.z, f3.w};
    #pragma unroll
    for (int cc = 0; cc < 16; ++cc) {
        float gc = g[cc];
        float4 w0 = wrow[cc * 4 + 0];
        float4 w1 = wrow[cc * 4 + 1];
        float4 w2 = wrow[cc * 4 + 2];
        float4 w3 = wrow[cc * 4 + 3];
        acc[0]  += gc * w0.x; acc[1]  += gc * w0.y; acc[2]  += gc * w0.z; acc[3]  += gc * w0.w;
        acc[4]  += gc * w1.x; acc[5]  += gc * w1.y; acc[6]  += gc * w1.z; acc[7]  += gc * w1.w;
        acc[8]  += gc * w2.x; acc[9]  += gc * w2.y; acc[10] += gc * w2.z; acc[11] += gc * w2.w;
        acc[12] += gc * w3.x; acc[13] += gc * w3.y; acc[14] += gc * w3.z; acc[15] += gc * w3.w;
    }
}

// ---------------- K1: compact + k-sorted entry list (idx,k | vmpos sideband) + rowstart + conv0 --
__global__ __launch_bounds__(128) void k1_compact_conv0(
    const float* __restrict__ feats,  // [N,4]
    const int* __restrict__ nbr,      // [N,27]
    const float* __restrict__ W,      // [27,4,16]
    const float* __restrict__ s, const float* __restrict__ b,
    int* __restrict__ gEnt,           // [NTILES,ETG]  (idx<<5)|k, k-sorted
    unsigned short* __restrict__ gVm, // [NTILES,ETG]  voxel-major row position
    int* __restrict__ rowstartG,      // [NTILES,TILE+1] exclusive scan of cnt (last = total)
    float* __restrict__ x) {          // [N,16]
    __shared__ int   lnbr[TILE * 27]; // 13.8 KB
    __shared__ float Wl[27 * 68];     // 7.3 KB
    __shared__ int   khist[27];
    __shared__ int   kbase[27];
    __shared__ int   rs[TILE];
    __shared__ int   eloc[ETG];       // 4 KB
    __shared__ unsigned short evm[ETG]; // 2 KB
    int t = threadIdx.x;
    int tile = blockIdx.x;
    int base = tile * TILE;
    for (int i = t; i < 27 * 64; i += 128)
        Wl[(i >> 6) * 68 + (i & 63)] = W[i];
    if (t < 27) khist[t] = 0;
    int nv = NVOX - base; if (nv > TILE) nv = TILE;
    const int* gsrc = nbr + base * 27;
    for (int i = t; i < nv * 27; i += 128)
        lnbr[i] = gsrc[i];            // fully coalesced
    __syncthreads();

    int c = 0;
    int* row = lnbr + t * 27;
    if (t < nv) {
        #pragma unroll
        for (int k = 0; k < 27; ++k) {
            int idx = row[k];
            if (idx >= 0) {
                row[c] = (idx << 5) | k;   // in-place compaction (c <= k)
                atomicAdd(&khist[k], 1);
                ++c;
            }
        }
    }
    // inclusive scan of c over 128 threads (Hillis-Steele)
    rs[t] = c;
    __syncthreads();
    #pragma unroll
    for (int off = 1; off < TILE; off <<= 1) {
        int v = rs[t];
        if (t >= off) v += rs[t - off];
        __syncthreads();
        rs[t] = v;
        __syncthreads();
    }
    int excl = rs[t] - c;
    int total = rs[TILE - 1];
    int tot = total < ETG ? total : ETG;
    rowstartG[tile * (TILE + 1) + t] = excl < tot ? excl : tot;
    if (t == TILE - 1) rowstartG[tile * (TILE + 1) + TILE] = tot;
    if (t == 0) {
        int a = 0;
        for (int k = 0; k < 27; ++k) { kbase[k] = a; a += khist[k]; }
    }
    __syncthreads();
    if (t < 27) khist[t] = 0;          // reuse as per-bin cursor
    __syncthreads();
    if (t < nv) {
        for (int j = 0; j < c; ++j) {
            int e = row[j];
            int k = e & 31;
            int pos = kbase[k] + atomicAdd(&khist[k], 1);
            if (pos < ETG) {
                eloc[pos] = e;
                evm[pos] = (unsigned short)(excl + j);
            }
        }
    }
    __syncthreads();
    for (int i = t; i < tot; i += 128) {
        gEnt[tile * ETG + i] = eloc[i];    // coalesced dump
        gVm[tile * ETG + i]  = evm[i];
    }

    // conv0: uniform loop over this thread's compacted entries (from LDS)
    if (t >= nv) return;
    float acc[16];
    #pragma unroll
    for (int d = 0; d < 16; ++d) acc[d] = 0.f;
    int e = row[0];                   // c >= 1 (center k=13 always present)
    float4 f = *(const float4*)(feats + (e >> 5) * 4);
    int j = 0;
    while (true) {
        bool more = (++j < c);
        int en = e; float4 fn = f;
        if (more) {
            en = row[j];
            fn = *(const float4*)(feats + (en >> 5) * 4);
        }
        {
            const float4* wrow = (const float4*)(Wl + (e & 31) * 68);
            float g[4] = {f.x, f.y, f.z, f.w};
            #pragma unroll
            for (int cc = 0; cc < 4; ++cc) {
                float gc = g[cc];
                float4 w0 = wrow[cc * 4 + 0];
                float4 w1 = wrow[cc * 4 + 1];
                float4 w2 = wrow[cc * 4 + 2];
                float4 w3 = wrow[cc * 4 + 3];
                acc[0]  += gc * w0.x; acc[1]  += gc * w0.y; acc[2]  += gc * w0.z; acc[3]  += gc * w0.w;
                acc[4]  += gc * w1.x; acc[5]  += gc * w1.y; acc[6]  += gc * w1.z; acc[7]  += gc * w1.w;
                acc[8]  += gc * w2.x; acc[9]  += gc * w2.y; acc[10] += gc * w2.z; acc[11] += gc * w2.w;
                acc[12] += gc * w3.x; acc[13] += gc * w3.y; acc[14] += gc * w3.z; acc[15] += gc * w3.w;
            }
        }
        if (!more) break;
        e = en; f = fn;
    }
    int n = base + t;
    float4* o = (float4*)(x + n * 16);
    #pragma unroll
    for (int q = 0; q < 4; ++q) {
        float4 r;
        float v0 = acc[q * 4 + 0] * s[q * 4 + 0] + b[q * 4 + 0];
        float v1 = acc[q * 4 + 1] * s[q * 4 + 1] + b[q * 4 + 1];
        float v2 = acc[q * 4 + 2] * s[q * 4 + 2] + b[q * 4 + 2];
        float v3 = acc[q * 4 + 3] * s[q * 4 + 3] + b[q * 4 + 3];
        r.x = v0 > 0.f ? v0 : 0.f;
        r.y = v1 > 0.f ? v1 : 0.f;
        r.z = v2 > 0.f ? v2 : 0.f;
        r.w = v3 > 0.f ? v3 : 0.f;
        o[q] = r;
    }
}

// ---------------- windowed phase 1: k-uniform entry loop, W broadcast, LDS partial rows --------
__device__ __forceinline__ void conv_window(const float* __restrict__ fin,
                                            const int* __restrict__ ePtr,
                                            const unsigned short* __restrict__ vmPtr,
                                            int cntE, int lo,
                                            const float* __restrict__ W,
                                            float* __restrict__ partial, int t) {
    int i = t;
    if (i >= cntE) return;
    int e = ePtr[i];
    int vm = vmPtr[i];
    const float4* fp = (const float4*)(fin + (e >> 5) * 16);
    float4 f0 = fp[0], f1 = fp[1], f2 = fp[2], f3 = fp[3];
    while (true) {
        int i2 = i + TILE;
        bool more = (i2 < cntE);
        int e2 = e, vm2 = vm;
        float4 g0 = f0, g1 = f1, g2 = f2, g3 = f3;
        if (more) {
            e2 = ePtr[i2];            // prefetch next entry + feature row
            vm2 = vmPtr[i2];
            const float4* fq = (const float4*)(fin + (e2 >> 5) * 16);
            g0 = fq[0]; g1 = fq[1]; g2 = fq[2]; g3 = fq[3];
        }
        int wr = vm - lo;
        if (wr >= 0 && wr < WIN) {    // always true in the (overwhelmingly common) single-pass case
            int k = e & 31;           // wave-uniform (k-sorted) -> W loads broadcast, L1-resident
            float acc[16];
            #pragma unroll
            for (int d = 0; d < 16; ++d) acc[d] = 0.f;
            fma16x16((const float4*)(W + k * 256), f0, f1, f2, f3, acc);
            float4* pr = (float4*)(partial + wr * 16);
            int sw = wr & 3;
            #pragma unroll
            for (int q = 0; q < 4; ++q) {
                float4 r;
                r.x = acc[q * 4 + 0]; r.y = acc[q * 4 + 1];
                r.z = acc[q * 4 + 2]; r.w = acc[q * 4 + 3];
                pr[q ^ sw] = r;       // XOR-swizzled chunk -> bank spread
            }
        }
        if (!more) break;
        i = i2; e = e2; vm = vm2; f0 = g0; f1 = g1; f2 = g2; f3 = g3;
    }
}

// ---------------- K2: conv1 (16->16), relu(conv*s+b) ----------------
__global__ __launch_bounds__(128) void k2_conv1(
    const float* __restrict__ fin,    // x [N,16]
    const int* __restrict__ gEnt, const unsigned short* __restrict__ gVm,
    const int* __restrict__ rowstartG,
    const float* __restrict__ W,      // [27,16,16] global (L1 broadcast)
    const float* __restrict__ s, const float* __restrict__ b,
    float* __restrict__ out) {        // h [N,16]
    __shared__ float partial[WIN * 16];   // 32 KB
    __shared__ int   rs[TILE + 1];
    int t = threadIdx.x;
    int tile = blockIdx.x;
    if (t < TILE) rs[t] = rowstartG[tile * (TILE + 1) + t];
    if (t == 0) rs[TILE] = rowstartG[tile * (TILE + 1) + TILE];
    __syncthreads();
    int cntE = rs[TILE];
    int rstart = rs[t];
    int rend = rs[t + 1];
    int n = tile * TILE + t;
    float acc[16];
    #pragma unroll
    for (int d = 0; d < 16; ++d) acc[d] = 0.f;
    for (int lo = 0; lo < cntE; lo += WIN) {
        conv_window(fin, gEnt + tile * ETG, gVm + tile * ETG, cntE, lo, W, partial, t);
        __syncthreads();
        if (n < NVOX) {
            int a  = rstart > lo ? rstart : lo;
            int bd = rend < lo + WIN ? rend : lo + WIN;
            for (int r = a; r < bd; ++r) {
                int wr = r - lo;
                const float4* pr = (const float4*)(partial + wr * 16);
                int sw = wr & 3;
                #pragma unroll
                for (int q = 0; q < 4; ++q) {
                    float4 v = pr[q ^ sw];
                    acc[q * 4 + 0] += v.x; acc[q * 4 + 1] += v.y;
                    acc[q * 4 + 2] += v.z; acc[q * 4 + 3] += v.w;
                }
            }
        }
        __syncthreads();
    }
    if (n >= NVOX) return;
    float4* o = (float4*)(out + n * 16);
    #pragma unroll
    for (int q = 0; q < 4; ++q) {
        float4 r;
        float v0 = acc[q * 4 + 0] * s[q * 4 + 0] + b[q * 4 + 0];
        float v1 = acc[q * 4 + 1] * s[q * 4 + 1] + b[q * 4 + 1];
        float v2 = acc[q * 4 + 2] * s[q * 4 + 2] + b[q * 4 + 2];
        float v3 = acc[q * 4 + 3] * s[q * 4 + 3] + b[q * 4 + 3];
        r.x = v0 > 0.f ? v0 : 0.f;
        r.y = v1 > 0.f ? v1 : 0.f;
        r.z = v2 > 0.f ? v2 : 0.f;
        r.w = v3 > 0.f ? v3 : 0.f;
        o[q] = r;
    }
}

// ---------------- K3: conv2 + residual + relu + final 16->3 linear ----------------
__global__ __launch_bounds__(128) void k3_conv2_final(
    const float* __restrict__ fin,    // h [N,16]
    const int* __restrict__ gEnt, const unsigned short* __restrict__ gVm,
    const int* __restrict__ rowstartG,
    const float* __restrict__ W,      // [27,16,16]
    const float* __restrict__ s, const float* __restrict__ b,
    const float* __restrict__ idn,    // x [N,16]
    const float* __restrict__ Wlin,   // [16,3]
    const float* __restrict__ blin,   // [3]
    float* __restrict__ out) {        // [N,3]
    __shared__ float partial[WIN * 16];
    __shared__ int   rs[TILE + 1];
    int t = threadIdx.x;
    int tile = blockIdx.x;
    if (t < TILE) rs[t] = rowstartG[tile * (TILE + 1) + t];
    if (t == 0) rs[TILE] = rowstartG[tile * (TILE + 1) + TILE];
    __syncthreads();
    int cntE = rs[TILE];
    int rstart = rs[t];
    int rend = rs[t + 1];
    int n = tile * TILE + t;
    float acc[16];
    #pragma unroll
    for (int d = 0; d < 16; ++d) acc[d] = 0.f;
    for (int lo = 0; lo < cntE; lo += WIN) {
        conv_window(fin, gEnt + tile * ETG, gVm + tile * ETG, cntE, lo, W, partial, t);
        __syncthreads();
        if (n < NVOX) {
            int a  = rstart > lo ? rstart : lo;
            int bd = rend < lo + WIN ? rend : lo + WIN;
            for (int r = a; r < bd; ++r) {
                int wr = r - lo;
                const float4* pr = (const float4*)(partial + wr * 16);
                int sw = wr & 3;
                #pragma unroll
                for (int q = 0; q < 4; ++q) {
                    float4 v = pr[q ^ sw];
                    acc[q * 4 + 0] += v.x; acc[q * 4 + 1] += v.y;
                    acc[q * 4 + 2] += v.z; acc[q * 4 + 3] += v.w;
                }
            }
        }
        __syncthreads();
    }
    if (n >= NVOX) return;
    const float4* ip = (const float4*)(idn + n * 16);
    float4 i0 = ip[0], i1 = ip[1], i2 = ip[2], i3 = ip[3];
    float id[16] = {i0.x, i0.y, i0.z, i0.w, i1.x, i1.y, i1.z, i1.w,
                    i2.x, i2.y, i2.z, i2.w, i3.x, i3.y, i3.z, i3.w};
    float o0 = blin[0], o1 = blin[1], o2 = blin[2];
    #pragma unroll
    for (int d = 0; d < 16; ++d) {
        float v = acc[d] * s[d] + b[d] + id[d];
        v = v > 0.f ? v : 0.f;
        o0 += v * Wlin[d * 3 + 0];
        o1 += v * Wlin[d * 3 + 1];
        o2 += v * Wlin[d * 3 + 2];
    }
    out[n * 3 + 0] = o0;
    out[n * 3 + 1] = o1;
    out[n * 3 + 2] = o2;
}

extern "C" void kernel_launch(void* const* d_in, const int* in_sizes, int n_in,
                              void* d_out, int out_size, void* d_ws, size_t ws_size,
                              hipStream_t stream) {
    const float* feats = (const float*)d_in[0];
    const int*   nbr   = (const int*)d_in[1];
    const float* W0    = (const float*)d_in[2];
    const float* s0    = (const float*)d_in[3];
    const float* b0    = (const float*)d_in[4];
    const float* W1    = (const float*)d_in[5];
    const float* s1    = (const float*)d_in[6];
    const float* b1    = (const float*)d_in[7];
    const float* W2    = (const float*)d_in[8];
    const float* s2    = (const float*)d_in[9];
    const float* b2    = (const float*)d_in[10];
    const float* Wlin  = (const float*)d_in[11];
    const float* blin  = (const float*)d_in[12];
    float* out = (float*)d_out;

    char* ws = (char*)d_ws;
    int*            gEnt      = (int*)(ws);                // NTILES*ETG*4   = 6,402,048
    unsigned short* gVm       = (unsigned short*)(ws + 6402048);   // NTILES*ETG*2 = 3,201,024
    int*            rowstartG = (int*)(ws + 9603072);      // NTILES*129*4   =   806,508
    float*          x         = (float*)(ws + 10409600);   // 16*N*4         = 12,800,000
    float*          h         = (float*)(ws + 23209600);   // 16*N*4         = 12,800,000

    k1_compact_conv0<<<NTILES, TILE, 0, stream>>>(feats, nbr, W0, s0, b0, gEnt, gVm, rowstartG, x);
    k2_conv1<<<NTILES, TILE, 0, stream>>>(x, gEnt, gVm, rowstartG, W1, s1, b1, h);
    k3_conv2_final<<<NTILES, TILE, 0, stream>>>(h, gEnt, gVm, rowstartG, W2, s2, b2, x, Wlin, blin, out);
}

// Round 8
// 81.830 us; speedup vs baseline: 2.2745x; 1.5555x over previous
//
#include <hip/hip_runtime.h>

#define NVOX 200000
#define TILE 256
#define WINROWS 256
#define NWIN 5
#define ETG (NWIN * WINROWS)                // 1280 entry cap per 256-voxel tile (data max ~1024, R4 evidence)
#define NTILES ((NVOX + TILE - 1) / TILE)   // 782
#define NBINS (NWIN * 27)                   // 135

// ---------------- 16x16 FMA micro-kernel: acc[16] += g[16] @ W(16x16) from LDS (260-pitch rows) --
__device__ __forceinline__ void fma16x16(const float4* __restrict__ wrow,
                                         float4 f0, float4 f1, float4 f2, float4 f3,
                                         float acc[16]) {
    const float g[16] = {f0.x, f0.y, f0.z, f0.w, f1.x, f1.y, f1.z, f1.w,
                         f2.x, f2.y, f2.z, f2.w, f3.x, f3.y, f3.z, f3.w};
    #pragma unroll
    for (int cc = 0; cc < 16; ++cc) {
        float gc = g[cc];
        float4 w0 = wrow[cc * 4 + 0];
        float4 w1 = wrow[cc * 4 + 1];
        float4 w2 = wrow[cc * 4 + 2];
        float4 w3 = wrow[cc * 4 + 3];
        acc[0]  += gc * w0.x; acc[1]  += gc * w0.y; acc[2]  += gc * w0.z; acc[3]  += gc * w0.w;
        acc[4]  += gc * w1.x; acc[5]  += gc * w1.y; acc[6]  += gc * w1.z; acc[7]  += gc * w1.w;
        acc[8]  += gc * w2.x; acc[9]  += gc * w2.y; acc[10] += gc * w2.z; acc[11] += gc * w2.w;
        acc[12] += gc * w3.x; acc[13] += gc * w3.y; acc[14] += gc * w3.z; acc[15] += gc * w3.w;
    }
}

// ---------------- K1: compact + (window,k)-binned entry list + rowstart + conv0 ----------------
__global__ __launch_bounds__(256) void k1_compact_conv0(
    const float* __restrict__ feats,  // [N,4]
    const int* __restrict__ nbr,      // [N,27]
    const float* __restrict__ W,      // [27,4,16]
    const float* __restrict__ s, const float* __restrict__ b,
    int* __restrict__ gEnt,           // [NTILES,ETG]  (idx<<5)|k, sorted by (window,k)
    unsigned short* __restrict__ gVm, // [NTILES,ETG]  voxel-major row position
    int* __restrict__ rowstartG,      // [NTILES,TILE+1]
    int* __restrict__ wbaseG,         // [NTILES,NWIN+1] entry-range per window
    float* __restrict__ x) {          // [N,16]
    __shared__ int   lnbr[TILE * 27];             // 27648 B
    __shared__ __align__(16) float Wl[27 * 68];   //  7344 B
    __shared__ int   bhist[NBINS];                //   540 B
    __shared__ int   bbase[NBINS];                //   540 B
    __shared__ int   rs[TILE];                    //  1024 B
    __shared__ int   eloc[ETG];                   //  5120 B
    __shared__ unsigned short evm[ETG];           //  2560 B
    int t = threadIdx.x;
    int tile = blockIdx.x;
    int base = tile * TILE;
    for (int i = t; i < 27 * 64; i += 256)
        Wl[(i >> 6) * 68 + (i & 63)] = W[i];
    for (int i = t; i < NBINS; i += 256) bhist[i] = 0;
    int nv = NVOX - base; if (nv > TILE) nv = TILE;
    const int* gsrc = nbr + base * 27;
    for (int i = t; i < nv * 27; i += 256)
        lnbr[i] = gsrc[i];            // fully coalesced
    __syncthreads();

    // pass 1: in-place compaction
    int c = 0;
    int* row = lnbr + t * 27;
    if (t < nv) {
        #pragma unroll
        for (int k = 0; k < 27; ++k) {
            int idx = row[k];
            if (idx >= 0) { row[c] = (idx << 5) | k; ++c; }
        }
    }
    // inclusive scan of c (Hillis-Steele, 256)
    rs[t] = c;
    __syncthreads();
    #pragma unroll
    for (int off = 1; off < TILE; off <<= 1) {
        int v = rs[t];
        if (t >= off) v += rs[t - off];
        __syncthreads();
        rs[t] = v;
        __syncthreads();
    }
    int excl = rs[t] - c;
    int total = rs[TILE - 1];
    int tot = total < ETG ? total : ETG;
    rowstartG[tile * (TILE + 1) + t] = excl < tot ? excl : tot;
    if (t == TILE - 1) rowstartG[tile * (TILE + 1) + TILE] = tot;

    // pass 2: histogram by (window, k)
    for (int j = 0; j < c; ++j) {
        int vm = excl + j;
        if (vm < ETG) {
            int k = row[j] & 31;
            atomicAdd(&bhist[(vm >> 8) * 27 + k], 1);
        }
    }
    __syncthreads();
    if (t == 0) {
        int a = 0;
        for (int i = 0; i < NBINS; ++i) { bbase[i] = a; a += bhist[i]; }
        for (int w = 0; w < NWIN; ++w)
            wbaseG[tile * (NWIN + 1) + w] = bbase[w * 27];
        wbaseG[tile * (NWIN + 1) + NWIN] = a;   // == tot
    }
    __syncthreads();
    for (int i = t; i < NBINS; i += 256) bhist[i] = 0;  // reuse as cursor
    __syncthreads();
    // pass 3: scatter into (window,k)-sorted list
    for (int j = 0; j < c; ++j) {
        int vm = excl + j;
        if (vm < ETG) {
            int e = row[j];
            int bin = (vm >> 8) * 27 + (e & 31);
            int pos = bbase[bin] + atomicAdd(&bhist[bin], 1);
            eloc[pos] = e;
            evm[pos] = (unsigned short)vm;
        }
    }
    __syncthreads();
    for (int i = t; i < tot; i += 256) {
        gEnt[tile * ETG + i] = eloc[i];
        gVm[tile * ETG + i]  = evm[i];
    }

    // conv0: uniform loop over this thread's compacted entries (from LDS)
    if (t >= nv) return;
    float acc[16];
    #pragma unroll
    for (int d = 0; d < 16; ++d) acc[d] = 0.f;
    int e = row[0];                   // c >= 1 (center k=13 always present)
    float4 f = *(const float4*)(feats + (e >> 5) * 4);
    int j = 0;
    while (true) {
        bool more = (++j < c);
        int en = e; float4 fn = f;
        if (more) {
            en = row[j];
            fn = *(const float4*)(feats + (en >> 5) * 4);
        }
        {
            const float4* wrow = (const float4*)(Wl + (e & 31) * 68);
            float g[4] = {f.x, f.y, f.z, f.w};
            #pragma unroll
            for (int cc = 0; cc < 4; ++cc) {
                float gc = g[cc];
                float4 w0 = wrow[cc * 4 + 0];
                float4 w1 = wrow[cc * 4 + 1];
                float4 w2 = wrow[cc * 4 + 2];
                float4 w3 = wrow[cc * 4 + 3];
                acc[0]  += gc * w0.x; acc[1]  += gc * w0.y; acc[2]  += gc * w0.z; acc[3]  += gc * w0.w;
                acc[4]  += gc * w1.x; acc[5]  += gc * w1.y; acc[6]  += gc * w1.z; acc[7]  += gc * w1.w;
                acc[8]  += gc * w2.x; acc[9]  += gc * w2.y; acc[10] += gc * w2.z; acc[11] += gc * w2.w;
                acc[12] += gc * w3.x; acc[13] += gc * w3.y; acc[14] += gc * w3.z; acc[15] += gc * w3.w;
            }
        }
        if (!more) break;
        e = en; f = fn;
    }
    int n = base + t;
    float4* o = (float4*)(x + n * 16);
    #pragma unroll
    for (int q = 0; q < 4; ++q) {
        float4 r;
        float v0 = acc[q * 4 + 0] * s[q * 4 + 0] + b[q * 4 + 0];
        float v1 = acc[q * 4 + 1] * s[q * 4 + 1] + b[q * 4 + 1];
        float v2 = acc[q * 4 + 2] * s[q * 4 + 2] + b[q * 4 + 2];
        float v3 = acc[q * 4 + 3] * s[q * 4 + 3] + b[q * 4 + 3];
        r.x = v0 > 0.f ? v0 : 0.f;
        r.y = v1 > 0.f ? v1 : 0.f;
        r.z = v2 > 0.f ? v2 : 0.f;
        r.w = v3 > 0.f ? v3 : 0.f;
        o[q] = r;
    }
}

// ---------------- shared conv body for K2/K3: windowed phase1/phase2, acc in regs --------------
__device__ __forceinline__ void conv16_windowed(const float* __restrict__ fin,
                                                const int* __restrict__ gE,
                                                const unsigned short* __restrict__ gV,
                                                const int* __restrict__ wb,
                                                const float* __restrict__ Wl,  // LDS, 260-pitch
                                                float* __restrict__ partial,   // LDS, 20-pitch
                                                int rstart, int rend, int t,
                                                float acc[16]) {
    #pragma unroll
    for (int d = 0; d < 16; ++d) acc[d] = 0.f;
    for (int w = 0; w < NWIN; ++w) {
        int lo = w * WINROWS;
        int ebeg = wb[w], eend = wb[w + 1];
        // phase 1: compute partial rows for this window's entries (k-sorted within)
        for (int i = ebeg + t; i < eend; i += 256) {
            int e = gE[i];
            int vm = gV[i];
            const float4* fp = (const float4*)(fin + (e >> 5) * 16);
            float4 f0 = fp[0], f1 = fp[1], f2 = fp[2], f3 = fp[3];
            float pa[16];
            #pragma unroll
            for (int d = 0; d < 16; ++d) pa[d] = 0.f;
            fma16x16((const float4*)(Wl + (e & 31) * 260), f0, f1, f2, f3, pa);
            float4* pr = (float4*)(partial + (vm - lo) * 20);  // stride 20 -> 8 bank-start spread
            #pragma unroll
            for (int q = 0; q < 4; ++q) {
                float4 r;
                r.x = pa[q * 4 + 0]; r.y = pa[q * 4 + 1];
                r.z = pa[q * 4 + 2]; r.w = pa[q * 4 + 3];
                pr[q] = r;
            }
        }
        __syncthreads();
        // phase 2: drain this window's rows into per-voxel accumulators
        int a  = rstart > lo ? rstart : lo;
        int bd = rend < lo + WINROWS ? rend : lo + WINROWS;
        for (int r = a; r < bd; ++r) {
            const float4* pr = (const float4*)(partial + (r - lo) * 20);
            #pragma unroll
            for (int q = 0; q < 4; ++q) {
                float4 v = pr[q];
                acc[q * 4 + 0] += v.x; acc[q * 4 + 1] += v.y;
                acc[q * 4 + 2] += v.z; acc[q * 4 + 3] += v.w;
            }
        }
        __syncthreads();
    }
}

// ---------------- K2: conv1 (16->16), relu(conv*s+b) ----------------
__global__ __launch_bounds__(256, 3) void k2_conv1(
    const float* __restrict__ fin,    // x [N,16]
    const int* __restrict__ gEnt, const unsigned short* __restrict__ gVm,
    const int* __restrict__ rowstartG, const int* __restrict__ wbaseG,
    const float* __restrict__ W,      // [27,16,16]
    const float* __restrict__ s, const float* __restrict__ b,
    float* __restrict__ out) {        // h [N,16]
    __shared__ __align__(16) float Wl[27 * 260];        // 28080 B
    __shared__ __align__(16) float partial[WINROWS * 20]; // 20480 B
    __shared__ int rs[TILE + 1];
    __shared__ int wb[NWIN + 1];
    int t = threadIdx.x;
    int tile = blockIdx.x;
    for (int i = t; i < 27 * 256; i += 256)
        Wl[(i >> 8) * 260 + (i & 255)] = W[i];
    rs[t] = rowstartG[tile * (TILE + 1) + t];
    if (t == 0) rs[TILE] = rowstartG[tile * (TILE + 1) + TILE];
    if (t < NWIN + 1) wb[t] = wbaseG[tile * (NWIN + 1) + t];
    __syncthreads();
    int rstart = rs[t];
    int rend = rs[t + 1];
    float acc[16];
    conv16_windowed(fin, gEnt + tile * ETG, gVm + tile * ETG, wb, Wl, partial,
                    rstart, rend, t, acc);
    int n = tile * TILE + t;
    if (n >= NVOX) return;
    float4* o = (float4*)(out + n * 16);
    #pragma unroll
    for (int q = 0; q < 4; ++q) {
        float4 r;
        float v0 = acc[q * 4 + 0] * s[q * 4 + 0] + b[q * 4 + 0];
        float v1 = acc[q * 4 + 1] * s[q * 4 + 1] + b[q * 4 + 1];
        float v2 = acc[q * 4 + 2] * s[q * 4 + 2] + b[q * 4 + 2];
        float v3 = acc[q * 4 + 3] * s[q * 4 + 3] + b[q * 4 + 3];
        r.x = v0 > 0.f ? v0 : 0.f;
        r.y = v1 > 0.f ? v1 : 0.f;
        r.z = v2 > 0.f ? v2 : 0.f;
        r.w = v3 > 0.f ? v3 : 0.f;
        o[q] = r;
    }
}

// ---------------- K3: conv2 + residual + relu + final 16->3 linear ----------------
__global__ __launch_bounds__(256, 3) void k3_conv2_final(
    const float* __restrict__ fin,    // h [N,16]
    const int* __restrict__ gEnt, const unsigned short* __restrict__ gVm,
    const int* __restrict__ rowstartG, const int* __restrict__ wbaseG,
    const float* __restrict__ W,      // [27,16,16]
    const float* __restrict__ s, const float* __restrict__ b,
    const float* __restrict__ idn,    // x [N,16]
    const float* __restrict__ Wlin,   // [16,3]
    const float* __restrict__ blin,   // [3]
    float* __restrict__ out) {        // [N,3]
    __shared__ __align__(16) float Wl[27 * 260];
    __shared__ __align__(16) float partial[WINROWS * 20];
    __shared__ int rs[TILE + 1];
    __shared__ int wb[NWIN + 1];
    int t = threadIdx.x;
    int tile = blockIdx.x;
    for (int i = t; i < 27 * 256; i += 256)
        Wl[(i >> 8) * 260 + (i & 255)] = W[i];
    rs[t] = rowstartG[tile * (TILE + 1) + t];
    if (t == 0) rs[TILE] = rowstartG[tile * (TILE + 1) + TILE];
    if (t < NWIN + 1) wb[t] = wbaseG[tile * (NWIN + 1) + t];
    __syncthreads();
    int rstart = rs[t];
    int rend = rs[t + 1];
    float acc[16];
    conv16_windowed(fin, gEnt + tile * ETG, gVm + tile * ETG, wb, Wl, partial,
                    rstart, rend, t, acc);
    int n = tile * TILE + t;
    if (n >= NVOX) return;
    const float4* ip = (const float4*)(idn + n * 16);
    float4 i0 = ip[0], i1 = ip[1], i2 = ip[2], i3 = ip[3];
    float id[16] = {i0.x, i0.y, i0.z, i0.w, i1.x, i1.y, i1.z, i1.w,
                    i2.x, i2.y, i2.z, i2.w, i3.x, i3.y, i3.z, i3.w};
    float o0 = blin[0], o1 = blin[1], o2 = blin[2];
    #pragma unroll
    for (int d = 0; d < 16; ++d) {
        float v = acc[d] * s[d] + b[d] + id[d];
        v = v > 0.f ? v : 0.f;
        o0 += v * Wlin[d * 3 + 0];
        o1 += v * Wlin[d * 3 + 1];
        o2 += v * Wlin[d * 3 + 2];
    }
    out[n * 3 + 0] = o0;
    out[n * 3 + 1] = o1;
    out[n * 3 + 2] = o2;
}

extern "C" void kernel_launch(void* const* d_in, const int* in_sizes, int n_in,
                              void* d_out, int out_size, void* d_ws, size_t ws_size,
                              hipStream_t stream) {
    const float* feats = (const float*)d_in[0];
    const int*   nbr   = (const int*)d_in[1];
    const float* W0    = (const float*)d_in[2];
    const float* s0    = (const float*)d_in[3];
    const float* b0    = (const float*)d_in[4];
    const float* W1    = (const float*)d_in[5];
    const float* s1    = (const float*)d_in[6];
    const float* b1    = (const float*)d_in[7];
    const float* W2    = (const float*)d_in[8];
    const float* s2    = (const float*)d_in[9];
    const float* b2    = (const float*)d_in[10];
    const float* Wlin  = (const float*)d_in[11];
    const float* blin  = (const float*)d_in[12];
    float* out = (float*)d_out;

    char* ws = (char*)d_ws;
    int*            gEnt      = (int*)(ws);                        // 782*1280*4 = 4,003,840
    unsigned short* gVm       = (unsigned short*)(ws + 4003840);   // 782*1280*2 = 2,001,920
    int*            rowstartG = (int*)(ws + 6005760);              // 782*257*4  =   803,896
    int*            wbaseG    = (int*)(ws + 6809664);              // 782*6*4    =    18,768
    float*          x         = (float*)(ws + 6828448);            // 12,800,000
    float*          h         = (float*)(ws + 19628448);           // 12,800,000

    k1_compact_conv0<<<NTILES, TILE, 0, stream>>>(feats, nbr, W0, s0, b0,
                                                  gEnt, gVm, rowstartG, wbaseG, x);
    k2_conv1<<<NTILES, TILE, 0, stream>>>(x, gEnt, gVm, rowstartG, wbaseG, W1, s1, b1, h);
    k3_conv2_final<<<NTILES, TILE, 0, stream>>>(h, gEnt, gVm, rowstartG, wbaseG, W2, s2, b2,
                                                x, Wlin, blin, out);
}